// Round 1
// baseline (126.870 us; speedup 1.0000x reference)
//
#include <hip/hip_runtime.h>
#include <hip/hip_bf16.h>

#define DEG 32
#define K_KNOTS 7
#define NINT 6  // K-1 intervals

// Natural cubic spline with uniform knot spacing h. y[7] -> C[6] = (a,b,c,d).
// Mirrors reference: tridiag(main=4h, off=h) solve for interior 2nd derivs.
__device__ inline void spline_coeffs(const float* __restrict__ y, float h, float4* C) {
    float dy[NINT];
#pragma unroll
    for (int i = 0; i < NINT; ++i) dy[i] = (y[i + 1] - y[i]) / h;
    float rhs[5];
#pragma unroll
    for (int i = 0; i < 5; ++i) rhs[i] = 6.0f * (dy[i + 1] - dy[i]);
    // Thomas algorithm, n=5, diag=4h, off=h
    float cp[5], dp[5];
    float denom = 4.0f * h;
    cp[0] = h / denom;
    dp[0] = rhs[0] / denom;
#pragma unroll
    for (int i = 1; i < 5; ++i) {
        denom = 4.0f * h - h * cp[i - 1];
        cp[i] = h / denom;
        dp[i] = (rhs[i] - h * dp[i - 1]) / denom;
    }
    float M[K_KNOTS];
    M[0] = 0.0f; M[6] = 0.0f;
    M[5] = dp[4];
#pragma unroll
    for (int i = 3; i >= 0; --i) M[i + 1] = dp[i] - cp[i] * M[i + 2];
#pragma unroll
    for (int i = 0; i < NINT; ++i) {
        C[i].x = y[i];
        C[i].y = dy[i] - h * (2.0f * M[i] + M[i + 1]) * (1.0f / 6.0f);
        C[i].z = M[i] * 0.5f;
        C[i].w = (M[i + 1] - M[i]) / (6.0f * h);
    }
}

__device__ inline float spline_eval(const float4* __restrict__ C, float t0,
                                    float inv_h, float h, float x) {
    float u = (x - t0) * inv_h;
    int idx = (int)floorf(u);
    idx = idx < 0 ? 0 : (idx > NINT - 1 ? NINT - 1 : idx);
    float s = x - (t0 + (float)idx * h);
    float4 c = C[idx];
    return c.x + s * (c.y + s * (c.z + s * c.w));
}

// Lane-per-triplet: thread t -> edge e = t>>5, neighbor j = t&31.
// 32 lanes of an edge cooperatively read the contiguous neighbor block
// r[src[e]*32 .. src[e]*32+31] (384 B, coalesced), reduce via shfl_xor.
__global__ __launch_bounds__(256) void smeam_kernel(
    const float* __restrict__ r, const float* __restrict__ fc,
    const float* __restrict__ gc, const int* __restrict__ src,
    const int* __restrict__ dst, float* __restrict__ out, int E) {
    __shared__ float4 sF[NINT];
    __shared__ float4 sG[NINT];
    if (threadIdx.x == 0) {
        const float hR = 8.0f / 6.0f;   // radial knots: linspace(0,8,7)
        const float hA = 2.0f / 6.0f;   // angular knots: linspace(-1,1,7)
        float4 cf[NINT], cg[NINT];
        spline_coeffs(fc, hR, cf);
        spline_coeffs(gc, hA, cg);
#pragma unroll
        for (int i = 0; i < NINT; ++i) { sF[i] = cf[i]; sG[i] = cg[i]; }
    }
    __syncthreads();

    const float hR = 8.0f / 6.0f, invHR = 6.0f / 8.0f;
    const float hA = 2.0f / 6.0f, invHA = 3.0f;

    int t = blockIdx.x * blockDim.x + threadIdx.x;
    int e = t >> 5;
    int j = t & 31;
    if (e >= E) return;

    int a = src[e];        // uniform across the 32-lane group
    int de = dst[e];
    float r2x = r[3 * e + 0];
    float r2y = r[3 * e + 1];
    float r2z = r[3 * e + 2];
    float l2 = sqrtf(r2x * r2x + r2y * r2y + r2z * r2z);
    float f2 = spline_eval(sF, 0.0f, invHR, hR, l2);

    int k = a * DEG + j;   // contiguous across lanes j=0..31
    int s = src[k];
    float rkx = r[3 * k + 0];
    float rky = r[3 * k + 1];
    float rkz = r[3 * k + 2];
    // r1 = -r[k]
    float l1 = sqrtf(rkx * rkx + rky * rky + rkz * rkz);
    float dot = -(rkx * r2x + rky * r2y + rkz * r2z);
    float cosv = dot / (l1 * l2);
    cosv = fminf(fmaxf(cosv, -1.0f), 1.0f);

    float f1 = spline_eval(sF, 0.0f, invHR, hR, l1);
    float g = spline_eval(sG, -1.0f, invHA, hA, cosv);
    float m = f1 * f2 * g;
    float val = (s != de) ? m : 0.0f;

    // reduce across the 32 lanes of this edge (xor masks <32 stay in-half)
#pragma unroll
    for (int off = 16; off >= 1; off >>= 1) val += __shfl_xor(val, off, 64);
    if (j == 0) out[e] = val;
}

extern "C" void kernel_launch(void* const* d_in, const int* in_sizes, int n_in,
                              void* d_out, int out_size, void* d_ws, size_t ws_size,
                              hipStream_t stream) {
    const float* r   = (const float*)d_in[0];
    const float* fc  = (const float*)d_in[1];
    const float* gc  = (const float*)d_in[2];
    const int* src   = (const int*)d_in[3];
    const int* dst   = (const int*)d_in[4];
    // d_in[5] is deg (device scalar); setup fixes deg=32 and the 32-lane
    // mapping below is specialized to it.
    float* out = (float*)d_out;
    int E = in_sizes[3];
    long long T = (long long)E * DEG;
    int threads = 256;
    int blocks = (int)((T + threads - 1) / threads);
    smeam_kernel<<<blocks, threads, 0, stream>>>(r, fc, gc, src, dst, out, E);
}

// Round 2
// 116.149 us; speedup vs baseline: 1.0923x; 1.0923x over previous
//
#include <hip/hip_runtime.h>
#include <hip/hip_bf16.h>

#define DEG 32
#define K_KNOTS 7
#define NINT 6  // K-1 intervals

// Natural cubic spline with uniform knot spacing h. y[7] -> C[6] = (a,b,c,d).
// Mirrors reference: tridiag(main=4h, off=h) solve for interior 2nd derivs.
__device__ inline void spline_coeffs(const float* __restrict__ y, float h, float4* C) {
    float dy[NINT];
#pragma unroll
    for (int i = 0; i < NINT; ++i) dy[i] = (y[i + 1] - y[i]) / h;
    float rhs[5];
#pragma unroll
    for (int i = 0; i < 5; ++i) rhs[i] = 6.0f * (dy[i + 1] - dy[i]);
    // Thomas algorithm, n=5, diag=4h, off=h
    float cp[5], dp[5];
    float denom = 4.0f * h;
    cp[0] = h / denom;
    dp[0] = rhs[0] / denom;
#pragma unroll
    for (int i = 1; i < 5; ++i) {
        denom = 4.0f * h - h * cp[i - 1];
        cp[i] = h / denom;
        dp[i] = (rhs[i] - h * dp[i - 1]) / denom;
    }
    float M[K_KNOTS];
    M[0] = 0.0f; M[6] = 0.0f;
    M[5] = dp[4];
#pragma unroll
    for (int i = 3; i >= 0; --i) M[i + 1] = dp[i] - cp[i] * M[i + 2];
#pragma unroll
    for (int i = 0; i < NINT; ++i) {
        C[i].x = y[i];
        C[i].y = dy[i] - h * (2.0f * M[i] + M[i + 1]) * (1.0f / 6.0f);
        C[i].z = M[i] * 0.5f;
        C[i].w = (M[i + 1] - M[i]) / (6.0f * h);
    }
}

// Phase 1: per-edge. l = |r_e|, u_e = r_e/l, f_e = f(l). ws[e] = (ux,uy,uz,f).
__global__ __launch_bounds__(256) void edge_kernel(
    const float* __restrict__ r, const float* __restrict__ fc,
    float4* __restrict__ uf, int E) {
    __shared__ float4 sF[NINT];
    if (threadIdx.x == 0) {
        float4 c[NINT];
        spline_coeffs(fc, 8.0f / 6.0f, c);  // radial knots linspace(0,8,7)
#pragma unroll
        for (int i = 0; i < NINT; ++i) sF[i] = c[i];
    }
    __syncthreads();
    int e = blockIdx.x * blockDim.x + threadIdx.x;
    if (e >= E) return;
    float x = r[3 * e + 0];
    float y = r[3 * e + 1];
    float z = r[3 * e + 2];
    float l = sqrtf(x * x + y * y + z * z);
    float inv = 1.0f / l;
    // f(l): l >= 0 so trunc == floor; idx clamp handles extrapolation (l > 8)
    float u = l * (6.0f / 8.0f);
    int idx = (int)u;
    idx = idx < 0 ? 0 : (idx > NINT - 1 ? NINT - 1 : idx);
    float s = l - (8.0f / 6.0f) * (float)idx;
    float4 c = sF[idx];
    float f = c.x + s * (c.y + s * (c.z + s * c.w));
    uf[e] = make_float4(x * inv, y * inv, z * inv, f);
}

// Phase 2: lane-per-triplet. cos = -(u_k . u_e) (unit vectors -> no div/sqrt),
// val = f_k * f_e * g(cos), masked, 32-lane shfl reduction per edge.
__global__ __launch_bounds__(256) void triplet_kernel(
    const float4* __restrict__ uf, const float* __restrict__ gc,
    const int* __restrict__ src, const int* __restrict__ dst,
    float* __restrict__ out, int E) {
    __shared__ float4 sG[NINT];
    if (threadIdx.x == 0) {
        float4 c[NINT];
        spline_coeffs(gc, 2.0f / 6.0f, c);  // angular knots linspace(-1,1,7)
#pragma unroll
        for (int i = 0; i < NINT; ++i) sG[i] = c[i];
    }
    __syncthreads();

    int t = blockIdx.x * blockDim.x + threadIdx.x;
    int e = t >> 5;
    int j = t & 31;
    if (e >= E) return;

    int a = src[e];         // uniform across the 32-lane group
    int de = dst[e];
    float4 ue = uf[e];      // broadcast load

    int k = a * DEG + j;    // contiguous across lanes j=0..31
    int s2 = src[k];
    float4 uk = uf[k];      // coalesced 512 B per 32 lanes

    float cosv = -(uk.x * ue.x + uk.y * ue.y + uk.z * ue.z);
    cosv = fminf(fmaxf(cosv, -1.0f), 1.0f);

    // g(cos): cos in [-1,1] -> u in [0,6]; trunc == floor (u >= 0)
    float u = (cosv + 1.0f) * 3.0f;
    int idx = (int)u;
    idx = idx > NINT - 1 ? NINT - 1 : idx;
    float s = cosv - (-1.0f + (2.0f / 6.0f) * (float)idx);
    float4 c = sG[idx];
    float g = c.x + s * (c.y + s * (c.z + s * c.w));

    float val = (s2 != de) ? uk.w * ue.w * g : 0.0f;

    // reduce across the 32 lanes of this edge (xor masks <32 stay in-half)
#pragma unroll
    for (int off = 16; off >= 1; off >>= 1) val += __shfl_xor(val, off, 64);
    if (j == 0) out[e] = val;
}

extern "C" void kernel_launch(void* const* d_in, const int* in_sizes, int n_in,
                              void* d_out, int out_size, void* d_ws, size_t ws_size,
                              hipStream_t stream) {
    const float* r   = (const float*)d_in[0];
    const float* fc  = (const float*)d_in[1];
    const float* gc  = (const float*)d_in[2];
    const int* src   = (const int*)d_in[3];
    const int* dst   = (const int*)d_in[4];
    float* out = (float*)d_out;
    int E = in_sizes[3];

    float4* uf = (float4*)d_ws;  // E * 16 bytes

    int threads = 256;
    int blocks1 = (E + threads - 1) / threads;
    edge_kernel<<<blocks1, threads, 0, stream>>>(r, fc, uf, E);

    long long T = (long long)E * DEG;
    int blocks2 = (int)((T + threads - 1) / threads);
    triplet_kernel<<<blocks2, threads, 0, stream>>>(uf, gc, src, dst, out, E);
}

// Round 3
// 107.465 us; speedup vs baseline: 1.1806x; 1.0808x over previous
//
#include <hip/hip_runtime.h>
#include <hip/hip_fp16.h>

#define DEG 32
#define K_KNOTS 7
#define NINT 6  // K-1 intervals

// 8-byte packed edge record: unit vector (fp16 x3) + f-spline value (fp16).
// 320k edges * 8 B = 2.56 MB -> fits in one XCD's 4 MiB L2, so the random
// gather in phase 2 stays L2-resident per XCD (R2's 16B record = 5.1 MB
// thrashed all 8 XCD L2s -> 50 MB HBM/L3 refetch per dispatch).
struct UF8 { __half2 xy; __half2 zf; };

// Natural cubic spline with uniform knot spacing h. y[7] -> C[6] = (a,b,c,d).
// Mirrors reference: tridiag(main=4h, off=h) solve for interior 2nd derivs.
__device__ inline void spline_coeffs(const float* __restrict__ y, float h, float4* C) {
    float dy[NINT];
#pragma unroll
    for (int i = 0; i < NINT; ++i) dy[i] = (y[i + 1] - y[i]) / h;
    float rhs[5];
#pragma unroll
    for (int i = 0; i < 5; ++i) rhs[i] = 6.0f * (dy[i + 1] - dy[i]);
    // Thomas algorithm, n=5, diag=4h, off=h
    float cp[5], dp[5];
    float denom = 4.0f * h;
    cp[0] = h / denom;
    dp[0] = rhs[0] / denom;
#pragma unroll
    for (int i = 1; i < 5; ++i) {
        denom = 4.0f * h - h * cp[i - 1];
        cp[i] = h / denom;
        dp[i] = (rhs[i] - h * dp[i - 1]) / denom;
    }
    float M[K_KNOTS];
    M[0] = 0.0f; M[6] = 0.0f;
    M[5] = dp[4];
#pragma unroll
    for (int i = 3; i >= 0; --i) M[i + 1] = dp[i] - cp[i] * M[i + 2];
#pragma unroll
    for (int i = 0; i < NINT; ++i) {
        C[i].x = y[i];
        C[i].y = dy[i] - h * (2.0f * M[i] + M[i + 1]) * (1.0f / 6.0f);
        C[i].z = M[i] * 0.5f;
        C[i].w = (M[i + 1] - M[i]) / (6.0f * h);
    }
}

// Phase 1: per-edge. l = |r_e|, u_e = r_e/l, f_e = f(l); pack to 8 B.
__global__ __launch_bounds__(256) void edge_kernel(
    const float* __restrict__ r, const float* __restrict__ fc,
    UF8* __restrict__ uf, int E) {
    __shared__ float4 sF[NINT];
    if (threadIdx.x == 0) {
        float4 c[NINT];
        spline_coeffs(fc, 8.0f / 6.0f, c);  // radial knots linspace(0,8,7)
#pragma unroll
        for (int i = 0; i < NINT; ++i) sF[i] = c[i];
    }
    __syncthreads();
    int e = blockIdx.x * blockDim.x + threadIdx.x;
    if (e >= E) return;
    float x = r[3 * e + 0];
    float y = r[3 * e + 1];
    float z = r[3 * e + 2];
    float d = x * x + y * y + z * z;
    float rl = rsqrtf(d);
    float l = d * rl;          // |r|
    // f(l): l >= 0 so trunc == floor; idx clamp handles extrapolation (l > 8)
    float u = l * (6.0f / 8.0f);
    int idx = (int)u;
    idx = idx < 0 ? 0 : (idx > NINT - 1 ? NINT - 1 : idx);
    float s = l - (8.0f / 6.0f) * (float)idx;
    float4 c = sF[idx];
    float f = c.x + s * (c.y + s * (c.z + s * c.w));
    UF8 q;
    q.xy = __floats2half2_rn(x * rl, y * rl);
    q.zf = __floats2half2_rn(z * rl, f);
    uf[e] = q;
}

// Phase 2: lane-per-triplet. cos = -(u_k . u_e) (unit vectors -> no div/sqrt),
// per-lane term = f_k * g(cos) (masked), 32-lane shfl reduction, then the
// wave-uniform f_e factor applied once at the end.
__global__ __launch_bounds__(256) void triplet_kernel(
    const UF8* __restrict__ uf, const float* __restrict__ gc,
    const int* __restrict__ src, const int* __restrict__ dst,
    float* __restrict__ out, int E) {
    __shared__ float4 sG[NINT];
    if (threadIdx.x == 0) {
        float4 c[NINT];
        spline_coeffs(gc, 2.0f / 6.0f, c);  // angular knots linspace(-1,1,7)
#pragma unroll
        for (int i = 0; i < NINT; ++i) sG[i] = c[i];
    }
    __syncthreads();

    int t = blockIdx.x * blockDim.x + threadIdx.x;
    int e = t >> 5;
    int j = t & 31;
    if (e >= E) return;

    int a = src[e];          // uniform across the 32-lane group
    int de = dst[e];
    UF8 qe = uf[e];          // broadcast 8 B
    float2 exy = __half22float2(qe.xy);
    float2 ezf = __half22float2(qe.zf);

    int k = a * DEG + j;     // contiguous across lanes j=0..31
    int s2 = src[k];
    UF8 qk = uf[k];          // coalesced 256 B per 32 lanes, L2-resident
    float2 kxy = __half22float2(qk.xy);
    float2 kzf = __half22float2(qk.zf);

    float cosv = -(kxy.x * exy.x + kxy.y * exy.y + kzf.x * ezf.x);
    cosv = fminf(fmaxf(cosv, -1.0f), 1.0f);

    // g(cos): cos in [-1,1] -> u in [0,6]; trunc == floor (u >= 0)
    float u = (cosv + 1.0f) * 3.0f;
    int idx = (int)u;
    idx = idx > NINT - 1 ? NINT - 1 : idx;
    float s = cosv - (-1.0f + (2.0f / 6.0f) * (float)idx);
    float4 c = sG[idx];
    float g = c.x + s * (c.y + s * (c.z + s * c.w));

    float val = (s2 != de) ? kzf.y * g : 0.0f;  // f_k * g, masked

    // reduce across the 32 lanes of this edge (xor masks <32 stay in-half)
#pragma unroll
    for (int off = 16; off >= 1; off >>= 1) val += __shfl_xor(val, off, 64);
    if (j == 0) out[e] = ezf.y * val;           // * f_e once
}

extern "C" void kernel_launch(void* const* d_in, const int* in_sizes, int n_in,
                              void* d_out, int out_size, void* d_ws, size_t ws_size,
                              hipStream_t stream) {
    const float* r   = (const float*)d_in[0];
    const float* fc  = (const float*)d_in[1];
    const float* gc  = (const float*)d_in[2];
    const int* src   = (const int*)d_in[3];
    const int* dst   = (const int*)d_in[4];
    float* out = (float*)d_out;
    int E = in_sizes[3];

    UF8* uf = (UF8*)d_ws;  // E * 8 bytes

    int threads = 256;
    int blocks1 = (E + threads - 1) / threads;
    edge_kernel<<<blocks1, threads, 0, stream>>>(r, fc, uf, E);

    long long T = (long long)E * DEG;
    int blocks2 = (int)((T + threads - 1) / threads);
    triplet_kernel<<<blocks2, threads, 0, stream>>>(uf, gc, src, dst, out, E);
}

// Round 4
// 94.468 us; speedup vs baseline: 1.3430x; 1.1376x over previous
//
#include <hip/hip_runtime.h>
#include <hip/hip_fp16.h>

#define DEG 32
#define K_KNOTS 7
#define NINT 6  // K-1 intervals

typedef _Float16 half_t;
typedef _Float16 h2 __attribute__((ext_vector_type(2)));

// 8-byte packed edge record: unit vector (fp16 x3) + f-spline value (fp16),
// stored as two half2: (x,y) and (z,f). 320k edges * 8 B = 2.56 MB keeps the
// phase-2 random gather L2/L3-resident (R3: FETCH 19 MB, latency hidden).
union UF8 {
    uint2 u;
    struct { h2 xy; h2 zf; } h;
};

__device__ inline float fdot2(h2 a, h2 b, float c) {
#if __has_builtin(__builtin_amdgcn_fdot2)
    return __builtin_amdgcn_fdot2(a, b, c, false);
#else
    return (float)a.x * (float)b.x + (float)a.y * (float)b.y + c;
#endif
}

// Natural cubic spline with uniform knot spacing h. y[7] -> C[6] = (a,b,c,d).
// Mirrors reference: tridiag(main=4h, off=h) solve for interior 2nd derivs.
__device__ inline void spline_coeffs(const float* __restrict__ y, float h, float4* C) {
    float dy[NINT];
#pragma unroll
    for (int i = 0; i < NINT; ++i) dy[i] = (y[i + 1] - y[i]) / h;
    float rhs[5];
#pragma unroll
    for (int i = 0; i < 5; ++i) rhs[i] = 6.0f * (dy[i + 1] - dy[i]);
    // Thomas algorithm, n=5, diag=4h, off=h
    float cp[5], dp[5];
    float denom = 4.0f * h;
    cp[0] = h / denom;
    dp[0] = rhs[0] / denom;
#pragma unroll
    for (int i = 1; i < 5; ++i) {
        denom = 4.0f * h - h * cp[i - 1];
        cp[i] = h / denom;
        dp[i] = (rhs[i] - h * dp[i - 1]) / denom;
    }
    float M[K_KNOTS];
    M[0] = 0.0f; M[6] = 0.0f;
    M[5] = dp[4];
#pragma unroll
    for (int i = 3; i >= 0; --i) M[i + 1] = dp[i] - cp[i] * M[i + 2];
#pragma unroll
    for (int i = 0; i < NINT; ++i) {
        C[i].x = y[i];
        C[i].y = dy[i] - h * (2.0f * M[i] + M[i + 1]) * (1.0f / 6.0f);
        C[i].z = M[i] * 0.5f;
        C[i].w = (M[i + 1] - M[i]) / (6.0f * h);
    }
}

// Phase 1: per-edge. l = |r_e|, u_e = r_e/l, f_e = f(l); pack to 8 B.
__global__ __launch_bounds__(256) void edge_kernel(
    const float* __restrict__ r, const float* __restrict__ fc,
    uint2* __restrict__ uf, int E) {
    __shared__ float4 sF[NINT];
    if (threadIdx.x == 0) {
        float4 c[NINT];
        spline_coeffs(fc, 8.0f / 6.0f, c);  // radial knots linspace(0,8,7)
#pragma unroll
        for (int i = 0; i < NINT; ++i) sF[i] = c[i];
    }
    __syncthreads();
    int e = blockIdx.x * blockDim.x + threadIdx.x;
    if (e >= E) return;
    float x = r[3 * e + 0];
    float y = r[3 * e + 1];
    float z = r[3 * e + 2];
    float d = x * x + y * y + z * z;
    float rl = rsqrtf(d);
    float l = d * rl;          // |r|
    // f(l): l >= 0 so trunc == floor; idx clamp handles extrapolation (l > 8)
    float u = l * (6.0f / 8.0f);
    int idx = (int)u;
    idx = idx < 0 ? 0 : (idx > NINT - 1 ? NINT - 1 : idx);
    float s = l - (8.0f / 6.0f) * (float)idx;
    float4 c = sF[idx];
    float f = c.x + s * (c.y + s * (c.z + s * c.w));
    UF8 q;
    q.h.xy.x = (half_t)(x * rl);
    q.h.xy.y = (half_t)(y * rl);
    q.h.zf.x = (half_t)(z * rl);
    q.h.zf.y = (half_t)f;
    uf[e] = q.u;
}

// Phase 2: THREAD-per-edge. Each thread serially accumulates its 32 triplets:
//   acc = sum_j [src[k]!=dst[e]] f_k * g(-(u_k . u_e)),  out[e] = f_e * acc.
// vs R3 lane-per-triplet this removes the 5-round shfl reduction (10 instr
// per triplet), amortizes all e-side work 32x, and uses v_dot2_f32_f16
// (f16 products exact in f32) to kill the per-triplet cvt chain.
__global__ __launch_bounds__(256) void triplet_kernel(
    const uint2* __restrict__ uf, const float* __restrict__ gc,
    const int* __restrict__ src, const int* __restrict__ dst,
    float* __restrict__ out, int E) {
    __shared__ float4 sG[NINT];
    if (threadIdx.x == 0) {
        float4 c[NINT];
        spline_coeffs(gc, 2.0f / 6.0f, c);  // angular knots linspace(-1,1,7)
#pragma unroll
        for (int i = 0; i < NINT; ++i) sG[i] = c[i];
    }
    __syncthreads();

    int e = blockIdx.x * blockDim.x + threadIdx.x;
    if (e >= E) return;

    int a = src[e];
    int de = dst[e];
    UF8 qe; qe.u = uf[e];                      // coalesced 8 B
    // negated e-side unit vector, once per edge: cos = dot(u_k, -u_e)
    uint2 neg = qe.u;
    neg.x ^= 0x80008000u;                      // -(x,y)
    neg.y ^= 0x00008000u;                      // -(z), keep f
    h2 ne_xy = __builtin_bit_cast(h2, neg.x);
    h2 ne_zf = __builtin_bit_cast(h2, neg.y);
    h2 ne_z0; ne_z0.x = ne_zf.x; ne_z0.y = (half_t)0.0f;
    float fe = (float)qe.h.zf.y;

    const uint4* blk = (const uint4*)(uf + (size_t)a * DEG);  // 2 records/load
    const int2* sblk = (const int2*)(src + (size_t)a * DEG);

    float acc = 0.0f;
#pragma unroll
    for (int it = 0; it < DEG / 2; ++it) {
        uint4 q = blk[it];
        int2 sp = sblk[it];
#pragma unroll
        for (int half = 0; half < 2; ++half) {
            h2 kxy = __builtin_bit_cast(h2, half ? q.z : q.x);
            h2 kzf = __builtin_bit_cast(h2, half ? q.w : q.y);
            int s2 = half ? sp.y : sp.x;
            float cosv = fdot2(kxy, ne_xy, fdot2(kzf, ne_z0, 0.0f));
            cosv = fminf(fmaxf(cosv, -1.0f), 1.0f);
            // g(cos): cos in [-1,1] -> u in [0,6]; trunc == floor (u >= 0)
            float u = (cosv + 1.0f) * 3.0f;
            int idx = (int)u;
            idx = idx > NINT - 1 ? NINT - 1 : idx;
            float s = cosv - (-1.0f + (2.0f / 6.0f) * (float)idx);
            float4 c = sG[idx];
            float g = c.x + s * (c.y + s * (c.z + s * c.w));
            float fk = (float)kzf.y;
            float term = (s2 != de) ? fk * g : 0.0f;
            acc += term;
        }
    }
    out[e] = fe * acc;
}

extern "C" void kernel_launch(void* const* d_in, const int* in_sizes, int n_in,
                              void* d_out, int out_size, void* d_ws, size_t ws_size,
                              hipStream_t stream) {
    const float* r   = (const float*)d_in[0];
    const float* fc  = (const float*)d_in[1];
    const float* gc  = (const float*)d_in[2];
    const int* src   = (const int*)d_in[3];
    const int* dst   = (const int*)d_in[4];
    float* out = (float*)d_out;
    int E = in_sizes[3];

    uint2* uf = (uint2*)d_ws;  // E * 8 bytes

    int threads = 256;
    int blocks1 = (E + threads - 1) / threads;
    edge_kernel<<<blocks1, threads, 0, stream>>>(r, fc, uf, E);

    int blocks2 = (E + threads - 1) / threads;
    triplet_kernel<<<blocks2, threads, 0, stream>>>(uf, gc, src, dst, out, E);
}

// Round 5
// 81.521 us; speedup vs baseline: 1.5563x; 1.1588x over previous
//
#include <hip/hip_runtime.h>
#include <hip/hip_fp16.h>

#define DEG 32
#define K_KNOTS 7
#define NINT 6  // K-1 intervals

typedef _Float16 half_t;
typedef _Float16 h2 __attribute__((ext_vector_type(2)));

// 8-byte packed edge record: unit vector (fp16 x3) + f-spline value (fp16),
// stored as two half2: (x,y) and (z,f). 320k edges * 8 B = 2.56 MB keeps the
// phase-2 random gather L2-resident (R3/R4: FETCH ~19 MB).
union UF8 {
    uint2 u;
    struct { h2 xy; h2 zf; } h;
};

__device__ inline float fdot2(h2 a, h2 b, float c) {
#if __has_builtin(__builtin_amdgcn_fdot2)
    return __builtin_amdgcn_fdot2(a, b, c, false);
#else
    return (float)a.x * (float)b.x + (float)a.y * (float)b.y + c;
#endif
}

// Natural cubic spline with uniform knot spacing h. y[7] -> C[6] = (a,b,c,d).
// Mirrors reference: tridiag(main=4h, off=h) solve for interior 2nd derivs.
__device__ inline void spline_coeffs(const float* __restrict__ y, float h, float4* C) {
    float dy[NINT];
#pragma unroll
    for (int i = 0; i < NINT; ++i) dy[i] = (y[i + 1] - y[i]) / h;
    float rhs[5];
#pragma unroll
    for (int i = 0; i < 5; ++i) rhs[i] = 6.0f * (dy[i + 1] - dy[i]);
    // Thomas algorithm, n=5, diag=4h, off=h
    float cp[5], dp[5];
    float denom = 4.0f * h;
    cp[0] = h / denom;
    dp[0] = rhs[0] / denom;
#pragma unroll
    for (int i = 1; i < 5; ++i) {
        denom = 4.0f * h - h * cp[i - 1];
        cp[i] = h / denom;
        dp[i] = (rhs[i] - h * dp[i - 1]) / denom;
    }
    float M[K_KNOTS];
    M[0] = 0.0f; M[6] = 0.0f;
    M[5] = dp[4];
#pragma unroll
    for (int i = 3; i >= 0; --i) M[i + 1] = dp[i] - cp[i] * M[i + 2];
#pragma unroll
    for (int i = 0; i < NINT; ++i) {
        C[i].x = y[i];
        C[i].y = dy[i] - h * (2.0f * M[i] + M[i + 1]) * (1.0f / 6.0f);
        C[i].z = M[i] * 0.5f;
        C[i].w = (M[i + 1] - M[i]) / (6.0f * h);
    }
}

// Phase 1: per-edge. l = |r_e|, u_e = r_e/l, f_e = f(l); pack to 8 B.
__global__ __launch_bounds__(256) void edge_kernel(
    const float* __restrict__ r, const float* __restrict__ fc,
    uint2* __restrict__ uf, int E) {
    __shared__ float4 sF[NINT];
    if (threadIdx.x == 0) {
        float4 c[NINT];
        spline_coeffs(fc, 8.0f / 6.0f, c);  // radial knots linspace(0,8,7)
#pragma unroll
        for (int i = 0; i < NINT; ++i) sF[i] = c[i];
    }
    __syncthreads();
    int e = blockIdx.x * blockDim.x + threadIdx.x;
    if (e >= E) return;
    float x = r[3 * e + 0];
    float y = r[3 * e + 1];
    float z = r[3 * e + 2];
    float d = x * x + y * y + z * z;
    float rl = rsqrtf(d);
    float l = d * rl;          // |r|
    // f(l): l >= 0 so trunc == floor; idx clamp handles extrapolation (l > 8)
    float u = l * (6.0f / 8.0f);
    int idx = (int)u;
    idx = idx < 0 ? 0 : (idx > NINT - 1 ? NINT - 1 : idx);
    float s = l - (8.0f / 6.0f) * (float)idx;
    float4 c = sF[idx];
    float f = c.x + s * (c.y + s * (c.z + s * c.w));
    UF8 q;
    q.h.xy.x = (half_t)(x * rl);
    q.h.xy.y = (half_t)(y * rl);
    q.h.zf.x = (half_t)(z * rl);
    q.h.zf.y = (half_t)f;
    uf[e] = q.u;
}

// Phase 2: FOUR lanes per edge (R4 post-mortem: thread-per-edge made every
// vector load 64 scattered cache lines -> TA/L1 serialization; R3's 32-lane
// layout paid 10 shfl-instr/triplet). Lane group q=0..3 of edge e loads 64 B
// of the 256 B neighbor block -> for a fixed unroll slot the 4 lanes cover one
// contiguous cache line (16 segments/wave-instr, 4x fewer TA lookups), each
// lane serially accumulates its 8 triplets, then a 2-round shfl reduces the
// group. Numerics identical to R4.
__global__ __launch_bounds__(256) void triplet_kernel(
    const uint2* __restrict__ uf, const float* __restrict__ gc,
    const int* __restrict__ src, const int* __restrict__ dst,
    float* __restrict__ out, int E) {
    __shared__ float4 sG[NINT];
    if (threadIdx.x == 0) {
        float4 c[NINT];
        spline_coeffs(gc, 2.0f / 6.0f, c);  // angular knots linspace(-1,1,7)
#pragma unroll
        for (int i = 0; i < NINT; ++i) sG[i] = c[i];
    }
    __syncthreads();

    int t = blockIdx.x * blockDim.x + threadIdx.x;
    int e = t >> 2;          // 4 consecutive lanes share one edge
    int q = t & 3;           // lane's slice of the neighbor block
    if (e >= E) return;

    int a = src[e];          // same addr for the 4 group lanes
    int de = dst[e];
    UF8 qe; qe.u = uf[e];
    // negated e-side unit vector, once: cos = dot(u_k, -u_e)
    uint2 neg = qe.u;
    neg.x ^= 0x80008000u;    // -(x,y)
    neg.y ^= 0x00008000u;    // -(z), keep f
    h2 ne_xy = __builtin_bit_cast(h2, neg.x);
    h2 ne_zf = __builtin_bit_cast(h2, neg.y);
    h2 ne_z0; ne_z0.x = ne_zf.x; ne_z0.y = (half_t)0.0f;
    float fe = (float)qe.h.zf.y;

    // lane's 8 records: uint4 slot it covers records q*8+2it, q*8+2it+1;
    // 4 lanes at slot it = contiguous 64 B.
    const uint4* blk = (const uint4*)(uf + (size_t)a * DEG);
    const int4* sblk = (const int4*)(src + (size_t)a * DEG);
    uint4 rq[4];
    int4 sq[2];
#pragma unroll
    for (int it = 0; it < 4; ++it) rq[it] = blk[q * 4 + it];
#pragma unroll
    for (int it = 0; it < 2; ++it) sq[it] = sblk[q * 2 + it];

    float acc = 0.0f;
#pragma unroll
    for (int rr = 0; rr < 8; ++rr) {
        uint4 qq = rq[rr >> 1];
        unsigned w0 = (rr & 1) ? qq.z : qq.x;
        unsigned w1 = (rr & 1) ? qq.w : qq.y;
        int4 sv = sq[rr >> 2];
        int s2 = (rr & 3) == 0 ? sv.x : (rr & 3) == 1 ? sv.y
               : (rr & 3) == 2 ? sv.z : sv.w;
        h2 kxy = __builtin_bit_cast(h2, w0);
        h2 kzf = __builtin_bit_cast(h2, w1);
        float cosv = fdot2(kxy, ne_xy, fdot2(kzf, ne_z0, 0.0f));
        cosv = fminf(fmaxf(cosv, -1.0f), 1.0f);
        // g(cos): cos in [-1,1] -> u in [0,6]; trunc == floor (u >= 0)
        float u = (cosv + 1.0f) * 3.0f;
        int idx = (int)u;
        idx = idx > NINT - 1 ? NINT - 1 : idx;
        float s = cosv - (-1.0f + (2.0f / 6.0f) * (float)idx);
        float4 c = sG[idx];
        float g = c.x + s * (c.y + s * (c.z + s * c.w));
        float fk = (float)kzf.y;
        float term = (s2 != de) ? fk * g : 0.0f;
        acc += term;
    }

    // reduce the 4-lane group (xor 1,2 stay within the group)
    acc += __shfl_xor(acc, 1, 64);
    acc += __shfl_xor(acc, 2, 64);
    if (q == 0) out[e] = fe * acc;
}

extern "C" void kernel_launch(void* const* d_in, const int* in_sizes, int n_in,
                              void* d_out, int out_size, void* d_ws, size_t ws_size,
                              hipStream_t stream) {
    const float* r   = (const float*)d_in[0];
    const float* fc  = (const float*)d_in[1];
    const float* gc  = (const float*)d_in[2];
    const int* src   = (const int*)d_in[3];
    const int* dst   = (const int*)d_in[4];
    float* out = (float*)d_out;
    int E = in_sizes[3];

    uint2* uf = (uint2*)d_ws;  // E * 8 bytes

    int threads = 256;
    int blocks1 = (E + threads - 1) / threads;
    edge_kernel<<<blocks1, threads, 0, stream>>>(r, fc, uf, E);

    long long T2 = (long long)E * 4;   // 4 lanes per edge
    int blocks2 = (int)((T2 + threads - 1) / threads);
    triplet_kernel<<<blocks2, threads, 0, stream>>>(uf, gc, src, dst, out, E);
}